// Round 11
// baseline (167.678 us; speedup 1.0000x reference)
//
#include <hip/hip_runtime.h>
#include <math.h>

// Margin loss with distance-weighted sampling — expectation form.
// R15: isolate the 512-thread shape. R14 (131.5us best) showed the tail
// is ~60us fixed harness overhead (launch-count-invariant: R13 1-launch
// tail=64, R14 2-launch=65.6, R12 3-launch=74); only gram's 65.9us is
// controllable (35.6us VALU-busy + ~30us stall at 8 waves/CU, LDS-capped
// 2 blocks). R6/R10's 512-thr attempts were conflated with K-split
// staging rounds + atomic storms. This round changes ONE thing vs R14:
// 8 waves (32x64 wave tiles) over the same 128x128 tile with the same
// full 64KB single-shot staging -> LDS 67KB, still 2 blocks/CU, but
// 16 waves/CU (VGPR must stay <=128: acc[2][4]=32 AGPR, R10 measured 80
// at this shape). Identical: fused f2bf staging, det P-store, LDS-atomic
// cross-wave combine (R10's verified mapping), R14 final.

#define NROWS 8192
#define DDIM  128
#define NPAIRF 7.0f
#define BT 128
#define NTILE (NROWS / BT)                    // 64
#define NPAIRS (NTILE * (NTILE + 1) / 2)      // 2080
#define LW2_SHIFT 57.70780163555852f          // 40 / ln2
#define FINAL_BLOCKS 256

typedef short bf16x8 __attribute__((ext_vector_type(8)));   // 8 bf16 = 4 VGPRs
typedef float f32x4  __attribute__((ext_vector_type(4)));   // MFMA C/D

template <bool B> struct BoolK { static constexpr bool value = B; };

__device__ __forceinline__ unsigned short f2bf(float f) {
    unsigned int u = __float_as_uint(f);
    return (unsigned short)((u + 0x7fffu + ((u >> 16) & 1u)) >> 16);   // RNE
}

// stage one 128x128 tile from f32 x into swizzled bf16 LDS (512 threads)
__device__ __forceinline__ void stage_from_x(const float* __restrict__ x,
        int base_row, unsigned short* buf, int tid) {
#pragma unroll
    for (int t = 0; t < 4; t++) {
        int s = tid + t * 512;
        int row = s >> 4;
        int kb = s & 15;
        int phys = row * 16 + (kb ^ (row & 7));
        const float4* src = (const float4*)&x[(size_t)(base_row + row) * DDIM + kb * 8];
        float4 v0 = src[0], v1 = src[1];
        uint4 pk;
        pk.x = (unsigned)f2bf(v0.x) | ((unsigned)f2bf(v0.y) << 16);
        pk.y = (unsigned)f2bf(v0.z) | ((unsigned)f2bf(v0.w) << 16);
        pk.z = (unsigned)f2bf(v1.x) | ((unsigned)f2bf(v1.y) << 16);
        pk.w = (unsigned)f2bf(v1.z) | ((unsigned)f2bf(v1.w) << 16);
        ((uint4*)buf)[phys] = pk;
    }
}

// fallback-only: zero rowacc + accum
__global__ void prep_kernel(float* __restrict__ rowacc, float* __restrict__ accum) {
    int t = blockIdx.x * 256 + threadIdx.x;
    if (t < NROWS * 3) rowacc[t] = 0.0f;
    if (t < 8) accum[t] = 0.0f;
}

// One block per unordered tile pair (I <= J). 8 waves, 32x64 wave tiles.
// DET: combined sums stored once to P[3][NTILE][NROWS]; else atomicAdd.
template <bool DET>
__global__ __launch_bounds__(512) void gram_kernel(
        const float* __restrict__ x, const float* __restrict__ beta,
        float* __restrict__ Pout, float* __restrict__ accum) {
    __shared__ unsigned short Abuf[BT * DDIM];   // 32 KB
    __shared__ unsigned short Bbuf[BT * DDIM];   // 32 KB
    __shared__ float comb_rows[BT][3];           // 1.5 KB
    __shared__ float comb_cols[BT][3];           // 1.5 KB

    if (DET && blockIdx.x == 0 && threadIdx.x == 0) accum[2] = 0.0f;  // ticket

    // decode blockIdx -> (I, J), I <= J  (row lengths 64, 63, ..., 1)
    int rem = blockIdx.x, I = 0;
    while (rem >= NTILE - I) { rem -= NTILE - I; ++I; }
    const int J = I + rem;
    const int row0 = I * BT, col0 = J * BT;

    const int tid = threadIdx.x;
    const int lane = tid & 63;
    const int wave = tid >> 6;                  // 0..7
    const int wy = wave >> 1, wx = wave & 1;    // wy: 4 row groups of 32; wx: 2 col groups of 64
    const int l15 = lane & 15, quad = lane >> 4;

    // zero the LDS combine buffers (ordered before adds by the staging barrier)
    if (tid < BT) {
        comb_rows[tid][0] = comb_rows[tid][1] = comb_rows[tid][2] = 0.0f;
    } else if (tid < 2 * BT) {
        int c = tid - BT;
        comb_cols[c][0] = comb_cols[c][1] = comb_cols[c][2] = 0.0f;
    }

    stage_from_x(x, row0, Abuf, tid);
    stage_from_x(x, col0, Bbuf, tid);

    f32x4 acc[2][4];
#pragma unroll
    for (int i = 0; i < 2; i++)
#pragma unroll
        for (int j = 0; j < 4; j++) acc[i][j] = (f32x4){0.f, 0.f, 0.f, 0.f};

    __syncthreads();

#pragma unroll
    for (int kc = 0; kc < 4; kc++) {
        bf16x8 bfr[4];
#pragma unroll
        for (int j = 0; j < 4; j++) {
            int rb = wx * 64 + j * 16 + l15;
            int pb = (kc * 4 + quad) ^ (rb & 7);
            bfr[j] = *(const bf16x8*)&Bbuf[(rb * 16 + pb) * 8];
        }
#pragma unroll
        for (int i = 0; i < 2; i++) {
            int ra = wy * 32 + i * 16 + l15;
            int pa = (kc * 4 + quad) ^ (ra & 7);
            bf16x8 af = *(const bf16x8*)&Abuf[(ra * 16 + pa) * 8];
#pragma unroll
            for (int j = 0; j < 4; j++)
                acc[i][j] = __builtin_amdgcn_mfma_f32_16x16x32_bf16(
                    af, bfr[j], acc[i][j], 0, 0, 0);
        }
    }

    // ---- epilogue ----
    float bpc4[4];
    int cloc4[4];
#pragma unroll
    for (int j = 0; j < 4; j++) {
        int cl = wx * 64 + j * 16 + l15;
        bpc4[j] = beta[col0 + cl] + 0.2f;
        cloc4[j] = cl >> 3;
    }
    float bpm8[8];
    int rloc8[8];
#pragma unroll
    for (int i = 0; i < 2; i++)
#pragma unroll
        for (int reg = 0; reg < 4; reg++) {
            int idx = i * 4 + reg;
            int rl = wy * 32 + i * 16 + quad * 4 + reg;
            bpm8[idx] = beta[row0 + rl] + 0.2f;
            rloc8[idx] = rl >> 3;
        }

    float ts0[8], ts1[8], ts2[8];
    float tc0[4], tc1[4], tc2[4];
#pragma unroll
    for (int k = 0; k < 8; k++) ts0[k] = ts1[k] = ts2[k] = 0.0f;
#pragma unroll
    for (int k = 0; k < 4; k++) tc0[k] = tc1[k] = tc2[k] = 0.0f;

    auto fold = [&](auto diag_c) {
        constexpr bool DIAG = decltype(diag_c)::value;
#pragma unroll
        for (int i = 0; i < 2; i++)
#pragma unroll
            for (int reg = 0; reg < 4; reg++) {
                const int idx = i * 4 + reg;
                const float bpm = bpm8[idx];
#pragma unroll
                for (int j = 0; j < 4; j++) {
                    float g = acc[i][j][reg];
                    float dist2 = fmaxf(fmaf(-2.0f, g, 2.0f), 0.0f);   // sq == 1
                    float d = __builtin_amdgcn_sqrtf(dist2 + 1e-8f);
                    float t = fmaxf(dist2, 0.25f);
                    float u = fmaf(-0.25f, t, 1.0f);
                    // w = 2^(-63*log2 t - 62.5*log2 u - 40/ln2) == e^(lw - 40)
                    float lw2 = fmaf(-63.0f, __builtin_amdgcn_logf(t),
                                fmaf(-62.5f, __builtin_amdgcn_logf(u), -LW2_SHIFT));
                    bool valid = t < 1.96f;
                    if (DIAG) valid = valid && (rloc8[idx] != cloc4[j]);
                    float w = valid ? __builtin_amdgcn_exp2f(lw2) : 0.0f;
                    float nlr = fmaxf(bpm - d, 0.0f);
                    ts0[idx] += w;
                    ts1[idx] = fmaf(w, nlr, ts1[idx]);
                    ts2[idx] += (nlr > 0.0f) ? w : 0.0f;
                    if (!DIAG) {
                        float nlc = fmaxf(bpc4[j] - d, 0.0f);
                        tc0[j] += w;
                        tc1[j] = fmaf(w, nlc, tc1[j]);
                        tc2[j] += (nlc > 0.0f) ? w : 0.0f;
                    }
                }
            }
    };
    if (I == J) fold(BoolK<true>{}); else fold(BoolK<false>{});

    // row fold: reduce 16 column-lanes; owner lane l15 == i*4+reg keeps row
    float r0 = 0.f, r1 = 0.f, r2 = 0.f;
#pragma unroll
    for (int idx = 0; idx < 8; idx++) {
        float t0 = ts0[idx], t1 = ts1[idx], t2 = ts2[idx];
#pragma unroll
        for (int off = 1; off < 16; off <<= 1) {
            t0 += __shfl_xor(t0, off);
            t1 += __shfl_xor(t1, off);
            t2 += __shfl_xor(t2, off);
        }
        if (l15 == idx) { r0 = t0; r1 = t1; r2 = t2; }
    }
    // owner lanes (l15<8) of both wx halves add into LDS
    if (l15 < 8) {
        int rowl = wy * 32 + (l15 >> 2) * 16 + quad * 4 + (l15 & 3);
        atomicAdd(&comb_rows[rowl][0], r0);
        atomicAdd(&comb_rows[rowl][1], r1);
        atomicAdd(&comb_rows[rowl][2], r2);
    }

    // col fold (off-diag): reduce across quad groups; lane quad==j keeps col j
    if (I != J) {
        float c0 = 0.f, c1 = 0.f, c2 = 0.f;
#pragma unroll
        for (int j = 0; j < 4; j++) {
            float t0 = tc0[j], t1 = tc1[j], t2 = tc2[j];
            t0 += __shfl_xor(t0, 16); t1 += __shfl_xor(t1, 16); t2 += __shfl_xor(t2, 16);
            t0 += __shfl_xor(t0, 32); t1 += __shfl_xor(t1, 32); t2 += __shfl_xor(t2, 32);
            if (quad == j) { c0 = t0; c1 = t1; c2 = t2; }
        }
        int coll = wx * 64 + quad * 16 + l15;
        atomicAdd(&comb_cols[coll][0], c0);
        atomicAdd(&comb_cols[coll][1], c1);
        atomicAdd(&comb_cols[coll][2], c2);
    }
    __syncthreads();

    // writeout: tid<128 rows (slot J), tid 128..255 cols (slot I, off-diag)
    if (tid < BT) {
        int rg = row0 + tid;
        if (DET) {
            Pout[(0 * NTILE + J) * NROWS + rg] = comb_rows[tid][0];
            Pout[(1 * NTILE + J) * NROWS + rg] = comb_rows[tid][1];
            Pout[(2 * NTILE + J) * NROWS + rg] = comb_rows[tid][2];
        } else {
            atomicAdd(&Pout[rg * 3 + 0], comb_rows[tid][0]);
            atomicAdd(&Pout[rg * 3 + 1], comb_rows[tid][1]);
            atomicAdd(&Pout[rg * 3 + 2], comb_rows[tid][2]);
        }
    } else if (tid < 2 * BT && I != J) {
        int c = tid - BT;
        int cg = col0 + c;
        if (DET) {
            Pout[(0 * NTILE + I) * NROWS + cg] = comb_cols[c][0];
            Pout[(1 * NTILE + I) * NROWS + cg] = comb_cols[c][1];
            Pout[(2 * NTILE + I) * NROWS + cg] = comb_cols[c][2];
        } else {
            atomicAdd(&Pout[cg * 3 + 0], comb_cols[c][0]);
            atomicAdd(&Pout[cg * 3 + 1], comb_cols[c][1]);
            atomicAdd(&Pout[cg * 3 + 2], comb_cols[c][2]);
        }
    }
}

// One thread per (anchor i, member p): 256 blocks x 256 thr. Block
// partials to blkpart slots (no zeroing needed); last-ticket block sums.
template <bool DET>
__global__ __launch_bounds__(256) void final_kernel(
        const float* __restrict__ x, const float* __restrict__ beta,
        const float* __restrict__ Pin, float* __restrict__ accum,
        float* __restrict__ blkpart, float* __restrict__ out) {
    __shared__ float sm[8];
    __shared__ bool amLast;
    const int tid = threadIdx.x;
    int t = blockIdx.x * 256 + tid;   // t = i*8 + p
    int i = t >> 3;
    int p = t & 7;
    int j = (i & ~7) + p;
    float betai = beta[i];
    const float4* xi = (const float4*)&x[(size_t)i * DDIM];
    const float4* xj = (const float4*)&x[(size_t)j * DDIM];
    float d2 = 0.0f;
#pragma unroll
    for (int k = 0; k < DDIM / 4; k++) {
        float4 va = xi[k], vb = xj[k];
        float dx = va.x - vb.x, dy = va.y - vb.y;
        float dz = va.z - vb.z, dw = va.w - vb.w;
        d2 = fmaf(dx, dx, fmaf(dy, dy, fmaf(dz, dz, fmaf(dw, dw, d2))));
    }
    float d = __builtin_amdgcn_sqrtf(d2 + 1e-8f);
    float nl = fmaxf(betai - d + 0.2f, 0.0f);
    float fb1 = nl;
    float fb2 = (nl > 0.0f) ? 1.0f : 0.0f;
    float num = 0.f, cnt = 0.f;
    if (j != i) {
        float pl = fmaxf(d - betai + 0.2f, 0.0f);
        num = pl;
        cnt = (pl > 0.0f) ? 1.0f : 0.0f;
    }
    // per-lane slice of the row's expectation sums
    float a0 = 0.f, a1 = 0.f, a2 = 0.f;
    if (DET) {
#pragma unroll
        for (int k = 0; k < 8; k++) {
            int s = p + k * 8;
            a0 += Pin[(0 * NTILE + s) * NROWS + i];
            a1 += Pin[(1 * NTILE + s) * NROWS + i];
            a2 += Pin[(2 * NTILE + s) * NROWS + i];
        }
    }
    // fold the 8 members of this row
#pragma unroll
    for (int off = 1; off < 8; off <<= 1) {
        num += __shfl_xor(num, off); cnt += __shfl_xor(cnt, off);
        fb1 += __shfl_xor(fb1, off); fb2 += __shfl_xor(fb2, off);
        a0 += __shfl_xor(a0, off);  a1 += __shfl_xor(a1, off);
        a2 += __shfl_xor(a2, off);
    }
    if (p == 0) {
        if (!DET) { a0 = Pin[i * 3 + 0]; a1 = Pin[i * 3 + 1]; a2 = Pin[i * 3 + 2]; }
        if (a0 > 0.0f) {
            num += NPAIRF * a1 / a0;
            cnt += NPAIRF * a2 / a0;
        } else {
            // degenerate row: uniform over all n columns; cross-block nl are all 0
            num += NPAIRF * fb1 / (float)NROWS;
            cnt += NPAIRF * fb2 / (float)NROWS;
        }
    } else {
        num = 0.f; cnt = 0.f;
    }
#pragma unroll
    for (int off = 8; off < 64; off <<= 1) {
        num += __shfl_xor(num, off);
        cnt += __shfl_xor(cnt, off);
    }
    int wv = tid >> 6, ln = tid & 63;
    if (ln == 0) { sm[wv] = num; sm[4 + wv] = cnt; }
    __syncthreads();
    if (tid == 0) {
        float n2 = 0.f, c2 = 0.f;
#pragma unroll
        for (int w = 0; w < 4; w++) { n2 += sm[w]; c2 += sm[4 + w]; }
        blkpart[blockIdx.x * 2 + 0] = n2;
        blkpart[blockIdx.x * 2 + 1] = c2;
        __threadfence();
        amLast = (atomicAdd(&accum[2], 1.0f) == (float)(gridDim.x - 1));
    }
    __syncthreads();
    if (amLast) {
        __threadfence();            // acquire: other blocks' partials visible
        float n = blkpart[tid * 2 + 0];
        float c = blkpart[tid * 2 + 1];
#pragma unroll
        for (int off = 1; off < 64; off <<= 1) {
            n += __shfl_xor(n, off);
            c += __shfl_xor(c, off);
        }
        if (ln == 0) { sm[wv] = n; sm[4 + wv] = c; }
        __syncthreads();
        if (tid == 0) {
            float nn = 0.f, cc = 0.f;
#pragma unroll
            for (int w = 0; w < 4; w++) { nn += sm[w]; cc += sm[4 + w]; }
            out[0] = nn / cc;
            accum[2] = 0.0f;        // self-clean for next replay
        }
    }
}

extern "C" void kernel_launch(void* const* d_in, const int* in_sizes, int n_in,
                              void* d_out, int out_size, void* d_ws, size_t ws_size,
                              hipStream_t stream) {
    const float* x = (const float*)d_in[0];
    const float* beta = (const float*)d_in[2];
    float* out = (float*)d_out;
    float* ws = (float*)d_ws;

    float* accum = ws;                                    // 64 floats ([2]=ticket)
    float* blkpart = ws + 64;                             // 256*2
    float* P = blkpart + FINAL_BLOCKS * 2;                // 3*64*8192 floats

    const size_t det_bytes = (64 + FINAL_BLOCKS * 2
                              + (size_t)3 * NTILE * NROWS) * 4;
    if (ws_size >= det_bytes) {
        gram_kernel<true><<<NPAIRS, 512, 0, stream>>>(x, beta, P, accum);
        final_kernel<true><<<FINAL_BLOCKS, 256, 0, stream>>>(x, beta, P, accum,
                                                             blkpart, out);
    } else {
        // fallback: 3-launch atomic path
        float* rowacc = blkpart + FINAL_BLOCKS * 2;       // 8192*3
        prep_kernel<<<(NROWS * 3 + 255) / 256, 256, 0, stream>>>(rowacc, accum);
        gram_kernel<false><<<NPAIRS, 512, 0, stream>>>(x, beta, rowacc, accum);
        final_kernel<false><<<FINAL_BLOCKS, 256, 0, stream>>>(x, beta, rowacc, accum,
                                                              blkpart, out);
    }
}

// Round 12
// 155.888 us; speedup vs baseline: 1.0756x; 1.0756x over previous
//
#include <hip/hip_runtime.h>
#include <math.h>

// Margin loss with distance-weighted sampling — expectation form.
// R16: LDS-residency on the proven shape. R15 closed the 512-thread
// question (3rd regression: 101us, occupancy never materialized). R14
// (131.5us total, gram 65.9) is best; its 68.6KB LDS caps 2 blocks/CU
// (8 waves, 25% static). This round: byte-identical R14 body, staging
// split into two 16KB K-halves (A dims 0-63 then 64-127, same for B)
// -> LDS 35.8KB -> 4 blocks/CU = 16 waves (50% cap). R8/R9's K-split
// failures were confounds (R8 launch-bounds spill; R9 sched_barrier +
// immediate-reduce). VGPR gate: must stay <=128 (4 waves/SIMD x 128 =
// full pool); R14 measured exactly 128 and the epilogue is untouched.
// Swizzle per half: phys = row*8 + (kb ^ (row&7))  (R8-verified).

#define NROWS 8192
#define DDIM  128
#define NPAIRF 7.0f
#define BT 128
#define NTILE (NROWS / BT)                    // 64
#define NPAIRS (NTILE * (NTILE + 1) / 2)      // 2080
#define LW2_SHIFT 57.70780163555852f          // 40 / ln2
#define FINAL_BLOCKS 256

typedef short bf16x8 __attribute__((ext_vector_type(8)));   // 8 bf16 = 4 VGPRs
typedef float f32x4  __attribute__((ext_vector_type(4)));   // MFMA C/D

template <bool B> struct BoolK { static constexpr bool value = B; };

__device__ __forceinline__ unsigned short f2bf(float f) {
    unsigned int u = __float_as_uint(f);
    return (unsigned short)((u + 0x7fffu + ((u >> 16) & 1u)) >> 16);   // RNE
}

// stage one 128x64 half-tile (dims kh*64..kh*64+63) from f32 x into
// swizzled bf16 LDS; 1024 uint4 slots, 4 per thread at 256 threads.
__device__ __forceinline__ void stage_half(const float* __restrict__ x,
        int base_row, int kh, unsigned short* buf, int tid) {
#pragma unroll
    for (int t = 0; t < 4; t++) {
        int s = tid + t * 256;          // 0..1023 slots (row*8 + kb)
        int row = s >> 3;
        int kb = s & 7;
        int phys = row * 8 + (kb ^ (row & 7));
        const float4* src =
            (const float4*)&x[(size_t)(base_row + row) * DDIM + kh * 64 + kb * 8];
        float4 v0 = src[0], v1 = src[1];
        uint4 pk;
        pk.x = (unsigned)f2bf(v0.x) | ((unsigned)f2bf(v0.y) << 16);
        pk.y = (unsigned)f2bf(v0.z) | ((unsigned)f2bf(v0.w) << 16);
        pk.z = (unsigned)f2bf(v1.x) | ((unsigned)f2bf(v1.y) << 16);
        pk.w = (unsigned)f2bf(v1.z) | ((unsigned)f2bf(v1.w) << 16);
        ((uint4*)buf)[phys] = pk;
    }
}

// fallback-only: zero rowacc + accum
__global__ void prep_kernel(float* __restrict__ rowacc, float* __restrict__ accum) {
    int t = blockIdx.x * 256 + threadIdx.x;
    if (t < NROWS * 3) rowacc[t] = 0.0f;
    if (t < 8) accum[t] = 0.0f;
}

// One block per unordered tile pair (I <= J). 4 waves, 64x64 wave tiles,
// R14 body with K-split 16KB staging halves (35.8KB LDS -> 4 blocks/CU).
// DET: combined sums stored once to P[3][NTILE][NROWS]; else atomicAdd.
template <bool DET>
__global__ __launch_bounds__(256) void gram_kernel(
        const float* __restrict__ x, const float* __restrict__ beta,
        float* __restrict__ Pout, float* __restrict__ accum) {
    __shared__ unsigned short Abuf[BT * 64];     // 16 KB (one K-half)
    __shared__ unsigned short Bbuf[BT * 64];     // 16 KB
    __shared__ float comb_rows[BT][3];           // 1.5 KB
    __shared__ float comb_cols[BT][3];           // 1.5 KB

    if (DET && blockIdx.x == 0 && threadIdx.x == 0) accum[2] = 0.0f;  // ticket

    // decode blockIdx -> (I, J), I <= J  (row lengths 64, 63, ..., 1)
    int rem = blockIdx.x, I = 0;
    while (rem >= NTILE - I) { rem -= NTILE - I; ++I; }
    const int J = I + rem;
    const int row0 = I * BT, col0 = J * BT;

    const int tid = threadIdx.x;
    const int lane = tid & 63;
    const int wave = tid >> 6;
    const int wy = wave >> 1, wx = wave & 1;
    const int l15 = lane & 15, quad = lane >> 4;

    f32x4 acc[4][4];
#pragma unroll
    for (int i = 0; i < 4; i++)
#pragma unroll
        for (int j = 0; j < 4; j++) acc[i][j] = (f32x4){0.f, 0.f, 0.f, 0.f};

    // two K-halves: stage 128 rows x 64 dims of A and B, 2 MFMA k-steps each
#pragma unroll
    for (int kh = 0; kh < 2; kh++) {
        if (kh) __syncthreads();                // drain reads of previous half
        stage_half(x, row0, kh, Abuf, tid);
        stage_half(x, col0, kh, Bbuf, tid);
        __syncthreads();

#pragma unroll
        for (int kcl = 0; kcl < 2; kcl++) {
            bf16x8 af[4], bfr[4];
#pragma unroll
            for (int i = 0; i < 4; i++) {
                int ra = wy * 64 + i * 16 + l15;
                int pa = (kcl * 4 + quad) ^ (ra & 7);
                af[i] = *(const bf16x8*)&Abuf[(ra * 8 + pa) * 8];
                int rb = wx * 64 + i * 16 + l15;
                int pb = (kcl * 4 + quad) ^ (rb & 7);
                bfr[i] = *(const bf16x8*)&Bbuf[(rb * 8 + pb) * 8];
            }
#pragma unroll
            for (int i = 0; i < 4; i++)
#pragma unroll
                for (int j = 0; j < 4; j++)
                    acc[i][j] = __builtin_amdgcn_mfma_f32_16x16x32_bf16(
                        af[i], bfr[j], acc[i][j], 0, 0, 0);
        }
    }

    // ---- epilogue (R14 body) ----
    float bpc4[4];
    int cloc4[4];
#pragma unroll
    for (int j = 0; j < 4; j++) {
        int cl = wx * 64 + j * 16 + l15;
        bpc4[j] = beta[col0 + cl] + 0.2f;
        cloc4[j] = cl >> 3;
    }
    float bpm16[16];
    int rloc16[16];
#pragma unroll
    for (int i = 0; i < 4; i++)
#pragma unroll
        for (int reg = 0; reg < 4; reg++) {
            int idx = i * 4 + reg;
            int rl = wy * 64 + i * 16 + quad * 4 + reg;
            bpm16[idx] = beta[row0 + rl] + 0.2f;
            rloc16[idx] = rl >> 3;
        }

    float ts0[16], ts1[16], ts2[16];
    float tc0[4], tc1[4], tc2[4];
#pragma unroll
    for (int k = 0; k < 16; k++) ts0[k] = ts1[k] = ts2[k] = 0.0f;
#pragma unroll
    for (int k = 0; k < 4; k++) tc0[k] = tc1[k] = tc2[k] = 0.0f;

    auto fold = [&](auto diag_c) {
        constexpr bool DIAG = decltype(diag_c)::value;
#pragma unroll
        for (int i = 0; i < 4; i++)
#pragma unroll
            for (int reg = 0; reg < 4; reg++) {
                const int idx = i * 4 + reg;
                const float bpm = bpm16[idx];
#pragma unroll
                for (int j = 0; j < 4; j++) {
                    float g = acc[i][j][reg];
                    float base = fmaf(-2.0f, g, 2.0f);             // sq == 1
                    float d = __builtin_amdgcn_sqrtf(fmaxf(base, 1e-8f));
                    float t = fmaxf(base, 0.25f);
                    float u = fmaf(-0.25f, t, 1.0f);
                    // w = 2^(-63*log2 t - 62.5*log2 u - 40/ln2) == e^(lw - 40)
                    float lw2 = fmaf(-63.0f, __builtin_amdgcn_logf(t),
                                fmaf(-62.5f, __builtin_amdgcn_logf(u), -LW2_SHIFT));
                    bool valid = t < 1.96f;
                    if (DIAG) valid = valid && (rloc16[idx] != cloc4[j]);
                    float w = valid ? __builtin_amdgcn_exp2f(lw2) : 0.0f;
                    float nlr = fmaxf(bpm - d, 0.0f);
                    ts0[idx] += w;
                    ts1[idx] = fmaf(w, nlr, ts1[idx]);
                    ts2[idx] += (nlr > 0.0f) ? w : 0.0f;
                    if (!DIAG) {
                        float nlc = fmaxf(bpc4[j] - d, 0.0f);
                        tc0[j] += w;
                        tc1[j] = fmaf(w, nlc, tc1[j]);
                        tc2[j] += (nlc > 0.0f) ? w : 0.0f;
                    }
                }
            }
    };
    if (I == J) fold(BoolK<true>{}); else fold(BoolK<false>{});

    // row fold: reduce 16 column-lanes; lane l15==idx keeps its row's sums
    float r0 = 0.f, r1 = 0.f, r2 = 0.f;
#pragma unroll
    for (int idx = 0; idx < 16; idx++) {
        float t0 = ts0[idx], t1 = ts1[idx], t2 = ts2[idx];
#pragma unroll
        for (int off = 1; off < 16; off <<= 1) {
            t0 += __shfl_xor(t0, off);
            t1 += __shfl_xor(t1, off);
            t2 += __shfl_xor(t2, off);
        }
        if (l15 == idx) { r0 = t0; r1 = t1; r2 = t2; }
    }
    const int rowl = wy * 64 + (l15 >> 2) * 16 + quad * 4 + (l15 & 3);

    // col fold: reduce across quad groups; lane quad==j keeps col j
    float c0 = 0.f, c1 = 0.f, c2 = 0.f;
#pragma unroll
    for (int j = 0; j < 4; j++) {
        float t0 = tc0[j], t1 = tc1[j], t2 = tc2[j];
        t0 += __shfl_xor(t0, 16); t1 += __shfl_xor(t1, 16); t2 += __shfl_xor(t2, 16);
        t0 += __shfl_xor(t0, 32); t1 += __shfl_xor(t1, 32); t2 += __shfl_xor(t2, 32);
        if (quad == j) { c0 = t0; c1 = t1; c2 = t2; }
    }
    const int coll = wx * 64 + quad * 16 + l15;

    // cross-wave combine: wx halves for rows, wy halves for cols
    if (wx == 0) {
        comb_rows[rowl][0] = r0; comb_rows[rowl][1] = r1; comb_rows[rowl][2] = r2;
    }
    if (wy == 0 && I != J) {
        comb_cols[coll][0] = c0; comb_cols[coll][1] = c1; comb_cols[coll][2] = c2;
    }
    __syncthreads();
    if (wx == 1) {
        float v0 = r0 + comb_rows[rowl][0];
        float v1 = r1 + comb_rows[rowl][1];
        float v2 = r2 + comb_rows[rowl][2];
        int rg = row0 + rowl;
        if (DET) {
            Pout[(0 * NTILE + J) * NROWS + rg] = v0;
            Pout[(1 * NTILE + J) * NROWS + rg] = v1;
            Pout[(2 * NTILE + J) * NROWS + rg] = v2;
        } else {
            atomicAdd(&Pout[rg * 3 + 0], v0);
            atomicAdd(&Pout[rg * 3 + 1], v1);
            atomicAdd(&Pout[rg * 3 + 2], v2);
        }
    }
    if (wy == 1 && I != J) {
        float v0 = c0 + comb_cols[coll][0];
        float v1 = c1 + comb_cols[coll][1];
        float v2 = c2 + comb_cols[coll][2];
        int cg = col0 + coll;
        if (DET) {
            Pout[(0 * NTILE + I) * NROWS + cg] = v0;
            Pout[(1 * NTILE + I) * NROWS + cg] = v1;
            Pout[(2 * NTILE + I) * NROWS + cg] = v2;
        } else {
            atomicAdd(&Pout[cg * 3 + 0], v0);
            atomicAdd(&Pout[cg * 3 + 1], v1);
            atomicAdd(&Pout[cg * 3 + 2], v2);
        }
    }
}

// One thread per (anchor i, member p): 256 blocks x 256 thr. Block
// partials to blkpart slots (no zeroing needed); last-ticket block sums.
template <bool DET>
__global__ __launch_bounds__(256) void final_kernel(
        const float* __restrict__ x, const float* __restrict__ beta,
        const float* __restrict__ Pin, float* __restrict__ accum,
        float* __restrict__ blkpart, float* __restrict__ out) {
    __shared__ float sm[8];
    __shared__ bool amLast;
    const int tid = threadIdx.x;
    int t = blockIdx.x * 256 + tid;   // t = i*8 + p
    int i = t >> 3;
    int p = t & 7;
    int j = (i & ~7) + p;
    float betai = beta[i];
    const float4* xi = (const float4*)&x[(size_t)i * DDIM];
    const float4* xj = (const float4*)&x[(size_t)j * DDIM];
    float d2 = 0.0f;
#pragma unroll
    for (int k = 0; k < DDIM / 4; k++) {
        float4 va = xi[k], vb = xj[k];
        float dx = va.x - vb.x, dy = va.y - vb.y;
        float dz = va.z - vb.z, dw = va.w - vb.w;
        d2 = fmaf(dx, dx, fmaf(dy, dy, fmaf(dz, dz, fmaf(dw, dw, d2))));
    }
    float d = __builtin_amdgcn_sqrtf(d2 + 1e-8f);
    float nl = fmaxf(betai - d + 0.2f, 0.0f);
    float fb1 = nl;
    float fb2 = (nl > 0.0f) ? 1.0f : 0.0f;
    float num = 0.f, cnt = 0.f;
    if (j != i) {
        float pl = fmaxf(d - betai + 0.2f, 0.0f);
        num = pl;
        cnt = (pl > 0.0f) ? 1.0f : 0.0f;
    }
    // per-lane slice of the row's expectation sums
    float a0 = 0.f, a1 = 0.f, a2 = 0.f;
    if (DET) {
#pragma unroll
        for (int k = 0; k < 8; k++) {
            int s = p + k * 8;
            a0 += Pin[(0 * NTILE + s) * NROWS + i];
            a1 += Pin[(1 * NTILE + s) * NROWS + i];
            a2 += Pin[(2 * NTILE + s) * NROWS + i];
        }
    }
    // fold the 8 members of this row
#pragma unroll
    for (int off = 1; off < 8; off <<= 1) {
        num += __shfl_xor(num, off); cnt += __shfl_xor(cnt, off);
        fb1 += __shfl_xor(fb1, off); fb2 += __shfl_xor(fb2, off);
        a0 += __shfl_xor(a0, off);  a1 += __shfl_xor(a1, off);
        a2 += __shfl_xor(a2, off);
    }
    if (p == 0) {
        if (!DET) { a0 = Pin[i * 3 + 0]; a1 = Pin[i * 3 + 1]; a2 = Pin[i * 3 + 2]; }
        if (a0 > 0.0f) {
            num += NPAIRF * a1 / a0;
            cnt += NPAIRF * a2 / a0;
        } else {
            // degenerate row: uniform over all n columns; cross-block nl are all 0
            num += NPAIRF * fb1 / (float)NROWS;
            cnt += NPAIRF * fb2 / (float)NROWS;
        }
    } else {
        num = 0.f; cnt = 0.f;
    }
#pragma unroll
    for (int off = 8; off < 64; off <<= 1) {
        num += __shfl_xor(num, off);
        cnt += __shfl_xor(cnt, off);
    }
    int wv = tid >> 6, ln = tid & 63;
    if (ln == 0) { sm[wv] = num; sm[4 + wv] = cnt; }
    __syncthreads();
    if (tid == 0) {
        float n2 = 0.f, c2 = 0.f;
#pragma unroll
        for (int w = 0; w < 4; w++) { n2 += sm[w]; c2 += sm[4 + w]; }
        blkpart[blockIdx.x * 2 + 0] = n2;
        blkpart[blockIdx.x * 2 + 1] = c2;
        __threadfence();
        amLast = (atomicAdd(&accum[2], 1.0f) == (float)(gridDim.x - 1));
    }
    __syncthreads();
    if (amLast) {
        __threadfence();            // acquire: other blocks' partials visible
        float n = blkpart[tid * 2 + 0];
        float c = blkpart[tid * 2 + 1];
#pragma unroll
        for (int off = 1; off < 64; off <<= 1) {
            n += __shfl_xor(n, off);
            c += __shfl_xor(c, off);
        }
        if (ln == 0) { sm[wv] = n; sm[4 + wv] = c; }
        __syncthreads();
        if (tid == 0) {
            float nn = 0.f, cc = 0.f;
#pragma unroll
            for (int w = 0; w < 4; w++) { nn += sm[w]; cc += sm[4 + w]; }
            out[0] = nn / cc;
            accum[2] = 0.0f;        // self-clean for next replay
        }
    }
}

extern "C" void kernel_launch(void* const* d_in, const int* in_sizes, int n_in,
                              void* d_out, int out_size, void* d_ws, size_t ws_size,
                              hipStream_t stream) {
    const float* x = (const float*)d_in[0];
    const float* beta = (const float*)d_in[2];
    float* out = (float*)d_out;
    float* ws = (float*)d_ws;

    float* accum = ws;                                    // 64 floats ([2]=ticket)
    float* blkpart = ws + 64;                             // 256*2
    float* P = blkpart + FINAL_BLOCKS * 2;                // 3*64*8192 floats

    const size_t det_bytes = (64 + FINAL_BLOCKS * 2
                              + (size_t)3 * NTILE * NROWS) * 4;
    if (ws_size >= det_bytes) {
        gram_kernel<true><<<NPAIRS, 256, 0, stream>>>(x, beta, P, accum);
        final_kernel<true><<<FINAL_BLOCKS, 256, 0, stream>>>(x, beta, P, accum,
                                                             blkpart, out);
    } else {
        // fallback: 3-launch atomic path
        float* rowacc = blkpart + FINAL_BLOCKS * 2;       // 8192*3
        prep_kernel<<<(NROWS * 3 + 255) / 256, 256, 0, stream>>>(rowacc, accum);
        gram_kernel<false><<<NPAIRS, 256, 0, stream>>>(x, beta, rowacc, accum);
        final_kernel<false><<<FINAL_BLOCKS, 256, 0, stream>>>(x, beta, rowacc, accum,
                                                              blkpart, out);
    }
}

// Round 14
// 133.610 us; speedup vs baseline: 1.2550x; 1.1667x over previous
//
#include <hip/hip_runtime.h>
#include <math.h>

// Margin loss with distance-weighted sampling — expectation form.
// R18: R17 was unscored (infra failure) and bundled two changes; this
// round de-risks to the single mechanism-backed piece. Byte-identical
// R14 body (131.5us best; gram 65.9, VGPR exactly 128) plus ONLY the
// XCD-chunked pair swizzle: p=(bid&7)*260+(bid>>3) (2080=8x260, exact,
// bijective). Pairs are I-major, so giving XCD k the contiguous range
// [k*260,(k+1)*260) makes consecutive co-resident blocks on one XCD
// share A-tiles in that XCD's L2: FETCH 18.8MB -> ~8-13MB predicted,
// staging latency drops from HBM (~900cy) to L2 (~200cy). Fold code
// unchanged from R14 (R16 law: any loop restructure inflates VGPR past
// the 128 cliff).

#define NROWS 8192
#define DDIM  128
#define NPAIRF 7.0f
#define BT 128
#define NTILE (NROWS / BT)                    // 64
#define NPAIRS (NTILE * (NTILE + 1) / 2)      // 2080
#define LW2_SHIFT 57.70780163555852f          // 40 / ln2
#define FINAL_BLOCKS 256

typedef short bf16x8 __attribute__((ext_vector_type(8)));   // 8 bf16 = 4 VGPRs
typedef float f32x4  __attribute__((ext_vector_type(4)));   // MFMA C/D

template <bool B> struct BoolK { static constexpr bool value = B; };

__device__ __forceinline__ unsigned short f2bf(float f) {
    unsigned int u = __float_as_uint(f);
    return (unsigned short)((u + 0x7fffu + ((u >> 16) & 1u)) >> 16);   // RNE
}

// stage one 128x128 tile from f32 x into swizzled bf16 LDS (256 threads)
__device__ __forceinline__ void stage_from_x(const float* __restrict__ x,
        int base_row, unsigned short* buf, int tid) {
#pragma unroll
    for (int t = 0; t < 8; t++) {
        int s = tid + t * 256;
        int row = s >> 4;
        int kb = s & 15;
        int phys = row * 16 + (kb ^ (row & 7));
        const float4* src = (const float4*)&x[(size_t)(base_row + row) * DDIM + kb * 8];
        float4 v0 = src[0], v1 = src[1];
        uint4 pk;
        pk.x = (unsigned)f2bf(v0.x) | ((unsigned)f2bf(v0.y) << 16);
        pk.y = (unsigned)f2bf(v0.z) | ((unsigned)f2bf(v0.w) << 16);
        pk.z = (unsigned)f2bf(v1.x) | ((unsigned)f2bf(v1.y) << 16);
        pk.w = (unsigned)f2bf(v1.z) | ((unsigned)f2bf(v1.w) << 16);
        ((uint4*)buf)[phys] = pk;
    }
}

// fallback-only: zero rowacc + accum
__global__ void prep_kernel(float* __restrict__ rowacc, float* __restrict__ accum) {
    int t = blockIdx.x * 256 + threadIdx.x;
    if (t < NROWS * 3) rowacc[t] = 0.0f;
    if (t < 8) accum[t] = 0.0f;
}

// One block per unordered tile pair (I <= J). 4 waves, 64x64 wave tiles.
// DET: combined sums stored once to P[3][NTILE][NROWS]; else atomicAdd.
template <bool DET>
__global__ __launch_bounds__(256, 2) void gram_kernel(
        const float* __restrict__ x, const float* __restrict__ beta,
        float* __restrict__ Pout, float* __restrict__ accum) {
    __shared__ unsigned short Abuf[BT * DDIM];   // 32 KB
    __shared__ unsigned short Bbuf[BT * DDIM];   // 32 KB
    __shared__ float comb_rows[BT][3];           // 1.5 KB
    __shared__ float comb_cols[BT][3];           // 1.5 KB

    if (DET && blockIdx.x == 0 && threadIdx.x == 0) accum[2] = 0.0f;  // ticket

    // XCD-chunked bijective swizzle: XCD k (blocks with bid%8==k) gets the
    // contiguous pair range [k*260, (k+1)*260) -> A-tile L2 locality.
    int p = (blockIdx.x & 7) * (NPAIRS / 8) + (blockIdx.x >> 3);

    // decode p -> (I, J), I <= J  (row lengths 64, 63, ..., 1)
    int rem = p, I = 0;
    while (rem >= NTILE - I) { rem -= NTILE - I; ++I; }
    const int J = I + rem;
    const int row0 = I * BT, col0 = J * BT;

    const int tid = threadIdx.x;
    const int lane = tid & 63;
    const int wave = tid >> 6;
    const int wy = wave >> 1, wx = wave & 1;
    const int l15 = lane & 15, quad = lane >> 4;

    stage_from_x(x, row0, Abuf, tid);
    stage_from_x(x, col0, Bbuf, tid);

    f32x4 acc[4][4];
#pragma unroll
    for (int i = 0; i < 4; i++)
#pragma unroll
        for (int j = 0; j < 4; j++) acc[i][j] = (f32x4){0.f, 0.f, 0.f, 0.f};

    __syncthreads();

#pragma unroll
    for (int kc = 0; kc < 4; kc++) {
        bf16x8 af[4], bfr[4];
#pragma unroll
        for (int i = 0; i < 4; i++) {
            int ra = wy * 64 + i * 16 + l15;
            int pa = (kc * 4 + quad) ^ (ra & 7);
            af[i] = *(const bf16x8*)&Abuf[(ra * 16 + pa) * 8];
            int rb = wx * 64 + i * 16 + l15;
            int pb = (kc * 4 + quad) ^ (rb & 7);
            bfr[i] = *(const bf16x8*)&Bbuf[(rb * 16 + pb) * 8];
        }
#pragma unroll
        for (int i = 0; i < 4; i++)
#pragma unroll
            for (int j = 0; j < 4; j++)
                acc[i][j] = __builtin_amdgcn_mfma_f32_16x16x32_bf16(
                    af[i], bfr[j], acc[i][j], 0, 0, 0);
    }

    // ---- epilogue (R14 body, unchanged) ----
    float bpc4[4];
    int cloc4[4];
#pragma unroll
    for (int j = 0; j < 4; j++) {
        int cl = wx * 64 + j * 16 + l15;
        bpc4[j] = beta[col0 + cl] + 0.2f;
        cloc4[j] = cl >> 3;
    }
    float bpm16[16];
    int rloc16[16];
#pragma unroll
    for (int i = 0; i < 4; i++)
#pragma unroll
        for (int reg = 0; reg < 4; reg++) {
            int idx = i * 4 + reg;
            int rl = wy * 64 + i * 16 + quad * 4 + reg;
            bpm16[idx] = beta[row0 + rl] + 0.2f;
            rloc16[idx] = rl >> 3;
        }

    float ts0[16], ts1[16], ts2[16];
    float tc0[4], tc1[4], tc2[4];
#pragma unroll
    for (int k = 0; k < 16; k++) ts0[k] = ts1[k] = ts2[k] = 0.0f;
#pragma unroll
    for (int k = 0; k < 4; k++) tc0[k] = tc1[k] = tc2[k] = 0.0f;

    auto fold = [&](auto diag_c) {
        constexpr bool DIAG = decltype(diag_c)::value;
#pragma unroll
        for (int i = 0; i < 4; i++)
#pragma unroll
            for (int reg = 0; reg < 4; reg++) {
                const int idx = i * 4 + reg;
                const float bpm = bpm16[idx];
#pragma unroll
                for (int j = 0; j < 4; j++) {
                    float g = acc[i][j][reg];
                    float dist2 = fmaxf(fmaf(-2.0f, g, 2.0f), 0.0f);   // sq == 1
                    float d = __builtin_amdgcn_sqrtf(dist2 + 1e-8f);
                    float t = fmaxf(dist2, 0.25f);
                    float u = fmaf(-0.25f, t, 1.0f);
                    // w = 2^(-63*log2 t - 62.5*log2 u - 40/ln2) == e^(lw - 40)
                    float lw2 = fmaf(-63.0f, __builtin_amdgcn_logf(t),
                                fmaf(-62.5f, __builtin_amdgcn_logf(u), -LW2_SHIFT));
                    bool valid = t < 1.96f;
                    if (DIAG) valid = valid && (rloc16[idx] != cloc4[j]);
                    float w = valid ? __builtin_amdgcn_exp2f(lw2) : 0.0f;
                    float nlr = fmaxf(bpm - d, 0.0f);
                    ts0[idx] += w;
                    ts1[idx] = fmaf(w, nlr, ts1[idx]);
                    ts2[idx] += (nlr > 0.0f) ? w : 0.0f;
                    if (!DIAG) {
                        float nlc = fmaxf(bpc4[j] - d, 0.0f);
                        tc0[j] += w;
                        tc1[j] = fmaf(w, nlc, tc1[j]);
                        tc2[j] += (nlc > 0.0f) ? w : 0.0f;
                    }
                }
            }
    };
    if (I == J) fold(BoolK<true>{}); else fold(BoolK<false>{});

    // row fold: reduce 16 column-lanes; lane l15==idx keeps its row's sums
    float r0 = 0.f, r1 = 0.f, r2 = 0.f;
#pragma unroll
    for (int idx = 0; idx < 16; idx++) {
        float t0 = ts0[idx], t1 = ts1[idx], t2 = ts2[idx];
#pragma unroll
        for (int off = 1; off < 16; off <<= 1) {
            t0 += __shfl_xor(t0, off);
            t1 += __shfl_xor(t1, off);
            t2 += __shfl_xor(t2, off);
        }
        if (l15 == idx) { r0 = t0; r1 = t1; r2 = t2; }
    }
    const int rowl = wy * 64 + (l15 >> 2) * 16 + quad * 4 + (l15 & 3);

    // col fold: reduce across quad groups; lane quad==j keeps col j
    float c0 = 0.f, c1 = 0.f, c2 = 0.f;
#pragma unroll
    for (int j = 0; j < 4; j++) {
        float t0 = tc0[j], t1 = tc1[j], t2 = tc2[j];
        t0 += __shfl_xor(t0, 16); t1 += __shfl_xor(t1, 16); t2 += __shfl_xor(t2, 16);
        t0 += __shfl_xor(t0, 32); t1 += __shfl_xor(t1, 32); t2 += __shfl_xor(t2, 32);
        if (quad == j) { c0 = t0; c1 = t1; c2 = t2; }
    }
    const int coll = wx * 64 + quad * 16 + l15;

    // cross-wave combine: wx halves for rows, wy halves for cols
    if (wx == 0) {
        comb_rows[rowl][0] = r0; comb_rows[rowl][1] = r1; comb_rows[rowl][2] = r2;
    }
    if (wy == 0 && I != J) {
        comb_cols[coll][0] = c0; comb_cols[coll][1] = c1; comb_cols[coll][2] = c2;
    }
    __syncthreads();
    if (wx == 1) {
        float v0 = r0 + comb_rows[rowl][0];
        float v1 = r1 + comb_rows[rowl][1];
        float v2 = r2 + comb_rows[rowl][2];
        int rg = row0 + rowl;
        if (DET) {
            Pout[(0 * NTILE + J) * NROWS + rg] = v0;
            Pout[(1 * NTILE + J) * NROWS + rg] = v1;
            Pout[(2 * NTILE + J) * NROWS + rg] = v2;
        } else {
            atomicAdd(&Pout[rg * 3 + 0], v0);
            atomicAdd(&Pout[rg * 3 + 1], v1);
            atomicAdd(&Pout[rg * 3 + 2], v2);
        }
    }
    if (wy == 1 && I != J) {
        float v0 = c0 + comb_cols[coll][0];
        float v1 = c1 + comb_cols[coll][1];
        float v2 = c2 + comb_cols[coll][2];
        int cg = col0 + coll;
        if (DET) {
            Pout[(0 * NTILE + I) * NROWS + cg] = v0;
            Pout[(1 * NTILE + I) * NROWS + cg] = v1;
            Pout[(2 * NTILE + I) * NROWS + cg] = v2;
        } else {
            atomicAdd(&Pout[cg * 3 + 0], v0);
            atomicAdd(&Pout[cg * 3 + 1], v1);
            atomicAdd(&Pout[cg * 3 + 2], v2);
        }
    }
}

// One thread per (anchor i, member p): 256 blocks x 256 thr. Block
// partials to blkpart slots (no zeroing needed); last-ticket block sums.
template <bool DET>
__global__ __launch_bounds__(256) void final_kernel(
        const float* __restrict__ x, const float* __restrict__ beta,
        const float* __restrict__ Pin, float* __restrict__ accum,
        float* __restrict__ blkpart, float* __restrict__ out) {
    __shared__ float sm[8];
    __shared__ bool amLast;
    const int tid = threadIdx.x;
    int t = blockIdx.x * 256 + tid;   // t = i*8 + p
    int i = t >> 3;
    int p = t & 7;
    int j = (i & ~7) + p;
    float betai = beta[i];
    const float4* xi = (const float4*)&x[(size_t)i * DDIM];
    const float4* xj = (const float4*)&x[(size_t)j * DDIM];
    float d2 = 0.0f;
#pragma unroll
    for (int k = 0; k < DDIM / 4; k++) {
        float4 va = xi[k], vb = xj[k];
        float dx = va.x - vb.x, dy = va.y - vb.y;
        float dz = va.z - vb.z, dw = va.w - vb.w;
        d2 = fmaf(dx, dx, fmaf(dy, dy, fmaf(dz, dz, fmaf(dw, dw, d2))));
    }
    float d = __builtin_amdgcn_sqrtf(d2 + 1e-8f);
    float nl = fmaxf(betai - d + 0.2f, 0.0f);
    float fb1 = nl;
    float fb2 = (nl > 0.0f) ? 1.0f : 0.0f;
    float num = 0.f, cnt = 0.f;
    if (j != i) {
        float pl = fmaxf(d - betai + 0.2f, 0.0f);
        num = pl;
        cnt = (pl > 0.0f) ? 1.0f : 0.0f;
    }
    // per-lane slice of the row's expectation sums
    float a0 = 0.f, a1 = 0.f, a2 = 0.f;
    if (DET) {
#pragma unroll
        for (int k = 0; k < 8; k++) {
            int s = p + k * 8;
            a0 += Pin[(0 * NTILE + s) * NROWS + i];
            a1 += Pin[(1 * NTILE + s) * NROWS + i];
            a2 += Pin[(2 * NTILE + s) * NROWS + i];
        }
    }
    // fold the 8 members of this row
#pragma unroll
    for (int off = 1; off < 8; off <<= 1) {
        num += __shfl_xor(num, off); cnt += __shfl_xor(cnt, off);
        fb1 += __shfl_xor(fb1, off); fb2 += __shfl_xor(fb2, off);
        a0 += __shfl_xor(a0, off);  a1 += __shfl_xor(a1, off);
        a2 += __shfl_xor(a2, off);
    }
    if (p == 0) {
        if (!DET) { a0 = Pin[i * 3 + 0]; a1 = Pin[i * 3 + 1]; a2 = Pin[i * 3 + 2]; }
        if (a0 > 0.0f) {
            num += NPAIRF * a1 / a0;
            cnt += NPAIRF * a2 / a0;
        } else {
            // degenerate row: uniform over all n columns; cross-block nl are all 0
            num += NPAIRF * fb1 / (float)NROWS;
            cnt += NPAIRF * fb2 / (float)NROWS;
        }
    } else {
        num = 0.f; cnt = 0.f;
    }
#pragma unroll
    for (int off = 8; off < 64; off <<= 1) {
        num += __shfl_xor(num, off);
        cnt += __shfl_xor(cnt, off);
    }
    int wv = tid >> 6, ln = tid & 63;
    if (ln == 0) { sm[wv] = num; sm[4 + wv] = cnt; }
    __syncthreads();
    if (tid == 0) {
        float n2 = 0.f, c2 = 0.f;
#pragma unroll
        for (int w = 0; w < 4; w++) { n2 += sm[w]; c2 += sm[4 + w]; }
        blkpart[blockIdx.x * 2 + 0] = n2;
        blkpart[blockIdx.x * 2 + 1] = c2;
        __threadfence();
        amLast = (atomicAdd(&accum[2], 1.0f) == (float)(gridDim.x - 1));
    }
    __syncthreads();
    if (amLast) {
        __threadfence();            // acquire: other blocks' partials visible
        float n = blkpart[tid * 2 + 0];
        float c = blkpart[tid * 2 + 1];
#pragma unroll
        for (int off = 1; off < 64; off <<= 1) {
            n += __shfl_xor(n, off);
            c += __shfl_xor(c, off);
        }
        if (ln == 0) { sm[wv] = n; sm[4 + wv] = c; }
        __syncthreads();
        if (tid == 0) {
            float nn = 0.f, cc = 0.f;
#pragma unroll
            for (int w = 0; w < 4; w++) { nn += sm[w]; cc += sm[4 + w]; }
            out[0] = nn / cc;
            accum[2] = 0.0f;        // self-clean for next replay
        }
    }
}

extern "C" void kernel_launch(void* const* d_in, const int* in_sizes, int n_in,
                              void* d_out, int out_size, void* d_ws, size_t ws_size,
                              hipStream_t stream) {
    const float* x = (const float*)d_in[0];
    const float* beta = (const float*)d_in[2];
    float* out = (float*)d_out;
    float* ws = (float*)d_ws;

    float* accum = ws;                                    // 64 floats ([2]=ticket)
    float* blkpart = ws + 64;                             // 256*2
    float* P = blkpart + FINAL_BLOCKS * 2;                // 3*64*8192 floats

    const size_t det_bytes = (64 + FINAL_BLOCKS * 2
                              + (size_t)3 * NTILE * NROWS) * 4;
    if (ws_size >= det_bytes) {
        gram_kernel<true><<<NPAIRS, 256, 0, stream>>>(x, beta, P, accum);
        final_kernel<true><<<FINAL_BLOCKS, 256, 0, stream>>>(x, beta, P, accum,
                                                             blkpart, out);
    } else {
        // fallback: 3-launch atomic path
        float* rowacc = blkpart + FINAL_BLOCKS * 2;       // 8192*3
        prep_kernel<<<(NROWS * 3 + 255) / 256, 256, 0, stream>>>(rowacc, accum);
        gram_kernel<false><<<NPAIRS, 256, 0, stream>>>(x, beta, rowacc, accum);
        final_kernel<false><<<FINAL_BLOCKS, 256, 0, stream>>>(x, beta, rowacc, accum,
                                                              blkpart, out);
    }
}